// Round 1
// baseline (773.947 us; speedup 1.0000x reference)
//
#include <hip/hip_runtime.h>
#include <hip/hip_bf16.h>
#include <cstdint>
#include <cstddef>

typedef __attribute__((ext_vector_type(8))) short s16x8;
typedef __attribute__((ext_vector_type(4))) float f32x4;
typedef __attribute__((ext_vector_type(8))) _Float16 h8;

#define TT 2048
#define BB 4
#define EE 1024
#define HH 16
#define DD 64
#define MR 8192   // T*B rows

__device__ __forceinline__ ushort f2bf(float f) {
  uint32_t u = __float_as_uint(f);
  u += 0x7fffu + ((u >> 16) & 1u);   // RNE
  return (ushort)(u >> 16);
}
__device__ __forceinline__ float bf2f(ushort u) {
  return __uint_as_float(((uint32_t)u) << 16);
}

// global -> LDS async copy, 16B per lane. LDS dest must be wave-uniform base + lane*16.
#define GL2L(g, l) __builtin_amdgcn_global_load_lds( \
    (__attribute__((address_space(1))) void*)(g), \
    (__attribute__((address_space(3))) void*)(l), 16, 0, 0)

// ---------------------------------------------------------------- cast fp32->bf16
__global__ void cast_f32_bf16(const float* __restrict__ in, ushort* __restrict__ out, int n4) {
  int stride = gridDim.x * blockDim.x;
  for (int i = blockIdx.x * blockDim.x + threadIdx.x; i < n4; i += stride) {
    float4 v = ((const float4*)in)[i];
    ushort4 o;
    o.x = f2bf(v.x); o.y = f2bf(v.y); o.z = f2bf(v.z); o.w = f2bf(v.w);
    ((ushort4*)out)[i] = o;
  }
}

// ---------------------------------------------------------------- QKV projection
// C[m][n] = sum_k A[m][k]*W[n][k] + bias[n];  m=(t*4+b), n = sec*1024 + h*64 + d
// Q scaled by 0.125, layout [b][h][t][d]; K same; V stored transposed [b][h][d][t].
__global__ __launch_bounds__(256) void gemm_qkv(
    const ushort* __restrict__ A, const ushort* __restrict__ W,
    const float* __restrict__ bias,
    ushort* __restrict__ Qb, ushort* __restrict__ Kb, ushort* __restrict__ Vt)
{
  __shared__ ushort As[128 * 32];
  __shared__ ushort Bs[128 * 32];
  const int K = EE;
  int tid = threadIdx.x;
  int bn = blockIdx.x, bm = blockIdx.y;
  int brow = bm * 128, bcol = bn * 128;
  int lane = tid & 63, wid = tid >> 6;
  int wm = wid >> 1, wn = wid & 1;
  int lr = lane & 15, kg = lane >> 4;

  f32x4 zero = {0.f, 0.f, 0.f, 0.f};
  f32x4 acc[4][4];
#pragma unroll
  for (int i = 0; i < 4; i++)
#pragma unroll
    for (int j = 0; j < 4; j++) acc[i][j] = zero;

  int r0 = tid >> 2, c0 = (tid & 3) * 8;
  const ushort* Abase = A + (size_t)brow * K;
  const ushort* Wbase = W + (size_t)bcol * K;

  for (int k0 = 0; k0 < K; k0 += 32) {
    __syncthreads();
    GL2L(Abase + (size_t)r0 * K + k0 + c0,        &As[tid * 8]);
    GL2L(Abase + (size_t)(r0 + 64) * K + k0 + c0, &As[(tid + 256) * 8]);
    GL2L(Wbase + (size_t)r0 * K + k0 + c0,        &Bs[tid * 8]);
    GL2L(Wbase + (size_t)(r0 + 64) * K + k0 + c0, &Bs[(tid + 256) * 8]);
    __syncthreads();
    s16x8 af[4], bfr[4];
#pragma unroll
    for (int i = 0; i < 4; i++) af[i]  = *(const s16x8*)&As[(wm * 64 + i * 16 + lr) * 32 + kg * 8];
#pragma unroll
    for (int j = 0; j < 4; j++) bfr[j] = *(const s16x8*)&Bs[(wn * 64 + j * 16 + lr) * 32 + kg * 8];
#pragma unroll
    for (int i = 0; i < 4; i++)
#pragma unroll
      for (int j = 0; j < 4; j++)
        acc[i][j] = __builtin_amdgcn_mfma_f32_16x16x32_bf16(af[i], bfr[j], acc[i][j], 0, 0, 0);
  }

#pragma unroll
  for (int i = 0; i < 4; i++)
#pragma unroll
    for (int j = 0; j < 4; j++) {
      int n = bcol + wn * 64 + j * 16 + lr;
      float bv = bias[n];
      int sec = n >> 10;
      int hd = n & 1023;
      int h = hd >> 6, d = hd & 63;
#pragma unroll
      for (int e = 0; e < 4; e++) {
        int m = brow + wm * 64 + i * 16 + kg * 4 + e;
        int t = m >> 2, b = m & 3;
        float v = acc[i][j][e] + bv;
        size_t hoff = (size_t)(b * HH + h);
        if (sec == 0)      Qb[(hoff * TT + t) * DD + d] = f2bf(v * 0.125f);
        else if (sec == 1) Kb[(hoff * TT + t) * DD + d] = f2bf(v);
        else               Vt[(hoff * DD + d) * TT + t] = f2bf(v);
      }
    }
}

// ---------------------------------------------------------------- scores + softmax
// block = (qt, h, bl): 16 q-rows x full 2048 keys. Scores in f16 LDS (64KB),
// wave-parallel softmax, write normalized weights bf16 to Wbuf[bl][h][t][s].
__global__ __launch_bounds__(256) void attn_scores(
    const ushort* __restrict__ Qb, const ushort* __restrict__ Kb,
    ushort* __restrict__ Wbuf, int b0)
{
  __shared__ _Float16 sc[16][2048];
  int qt = blockIdx.x, h = blockIdx.y, bl = blockIdx.z;
  int b = b0 + bl;
  int tid = threadIdx.x, lane = tid & 63, w = tid >> 6;
  int lr = lane & 15, kg = lane >> 4;

  const ushort* q  = Qb + ((size_t)(b * HH + h) * TT + qt * 16) * DD;
  const ushort* kp = Kb + ((size_t)(b * HH + h) * TT) * DD;

  s16x8 aq0 = *(const s16x8*)&q[lr * DD + kg * 8];
  s16x8 aq1 = *(const s16x8*)&q[lr * DD + 32 + kg * 8];

#pragma unroll 2
  for (int nt = w; nt < 128; nt += 4) {
    const ushort* kr = kp + (size_t)nt * 16 * DD;
    s16x8 bk0 = *(const s16x8*)&kr[lr * DD + kg * 8];
    s16x8 bk1 = *(const s16x8*)&kr[lr * DD + 32 + kg * 8];
    f32x4 c = {0.f, 0.f, 0.f, 0.f};
    c = __builtin_amdgcn_mfma_f32_16x16x32_bf16(aq0, bk0, c, 0, 0, 0);
    c = __builtin_amdgcn_mfma_f32_16x16x32_bf16(aq1, bk1, c, 0, 0, 0);
#pragma unroll
    for (int e = 0; e < 4; e++) sc[kg * 4 + e][nt * 16 + lr] = (_Float16)c[e];
  }
  __syncthreads();

#pragma unroll
  for (int u = 0; u < 4; ++u) {
    int r = w * 4 + u;
    const h8* rowp = (const h8*)&sc[r][0];
    float mx = -1e30f;
#pragma unroll
    for (int c = 0; c < 4; ++c) {
      h8 v = rowp[c * 64 + lane];
#pragma unroll
      for (int j = 0; j < 8; j++) mx = fmaxf(mx, (float)v[j]);
    }
#pragma unroll
    for (int o = 32; o; o >>= 1) mx = fmaxf(mx, __shfl_xor(mx, o));
    float l = 0.f;
    h8* roww = (h8*)&sc[r][0];
#pragma unroll
    for (int c = 0; c < 4; ++c) {
      h8 v = rowp[c * 64 + lane];
      h8 ev;
#pragma unroll
      for (int j = 0; j < 8; j++) { float e = __expf((float)v[j] - mx); l += e; ev[j] = (_Float16)e; }
      roww[c * 64 + lane] = ev;
    }
#pragma unroll
    for (int o = 32; o; o >>= 1) l += __shfl_xor(l, o);
    float inv = 1.f / l;
    ushort* wrow = Wbuf + ((size_t)(bl * HH + h) * TT + qt * 16 + r) * TT;
#pragma unroll
    for (int c = 0; c < 4; ++c) {
      h8 v = rowp[c * 64 + lane];
      s16x8 ov;
#pragma unroll
      for (int j = 0; j < 8; j++) ov[j] = (short)f2bf((float)v[j] * inv);
      *(s16x8*)&wrow[(c * 64 + lane) * 8] = ov;
    }
  }
}

// ---------------------------------------------------------------- head-average of weights
__global__ void avg_kernel(const ushort* __restrict__ Wbuf, float* __restrict__ avgp, int nb) {
  size_t per_b = (size_t)TT * (TT / 8);
  size_t total = (size_t)nb * per_b;
  size_t stride = (size_t)gridDim.x * blockDim.x;
  for (size_t cidx = (size_t)blockIdx.x * blockDim.x + threadIdx.x; cidx < total; cidx += stride) {
    int blc = (int)(cidx / per_b);
    size_t rr = cidx % per_b;
    int t = (int)(rr >> 8);
    int s0 = ((int)rr & 255) * 8;
    const ushort* wp = Wbuf + ((size_t)blc * HH * TT + t) * TT + s0;
    float a[8] = {0.f, 0.f, 0.f, 0.f, 0.f, 0.f, 0.f, 0.f};
#pragma unroll
    for (int h = 0; h < HH; ++h) {
      s16x8 v = *(const s16x8*)(wp + (size_t)h * TT * TT);
#pragma unroll
      for (int j = 0; j < 8; j++) a[j] += bf2f((ushort)v[j]);
    }
    float* dst = avgp + ((size_t)blc * TT + t) * TT + s0;
    float4 o0 = {a[0] * 0.0625f, a[1] * 0.0625f, a[2] * 0.0625f, a[3] * 0.0625f};
    float4 o1 = {a[4] * 0.0625f, a[5] * 0.0625f, a[6] * 0.0625f, a[7] * 0.0625f};
    ((float4*)dst)[0] = o0;
    ((float4*)dst)[1] = o1;
  }
}

// ---------------------------------------------------------------- PV: attn = W * V
// per (mt, h, bl): C[128 x 64] = Wbuf[128 x 2048] * V[2048 x 64]; V held as Vt [64][2048].
__global__ __launch_bounds__(256) void gemm_pv(
    const ushort* __restrict__ Wbuf, const ushort* __restrict__ Vt,
    ushort* __restrict__ attn, int b0)
{
  __shared__ ushort As[128 * 32];
  __shared__ ushort Bs[64 * 32];
  int mt = blockIdx.x, h = blockIdx.y, bl = blockIdx.z;
  int b = b0 + bl;
  int tid = threadIdx.x, lane = tid & 63, wid = tid >> 6;
  int lr = lane & 15, kg = lane >> 4;
  const ushort* A  = Wbuf + (size_t)(bl * HH + h) * TT * TT;
  const ushort* Bv = Vt + (size_t)(b * HH + h) * DD * TT;
  int brow = mt * 128;

  f32x4 zero = {0.f, 0.f, 0.f, 0.f};
  f32x4 acc[2][4];
#pragma unroll
  for (int i = 0; i < 2; i++)
#pragma unroll
    for (int j = 0; j < 4; j++) acc[i][j] = zero;

  int r0 = tid >> 2, c0 = (tid & 3) * 8;
  for (int k0 = 0; k0 < TT; k0 += 32) {
    __syncthreads();
    GL2L(A + (size_t)(brow + r0) * TT + k0 + c0,      &As[tid * 8]);
    GL2L(A + (size_t)(brow + r0 + 64) * TT + k0 + c0, &As[(tid + 256) * 8]);
    GL2L(Bv + (size_t)(tid >> 2) * TT + k0 + c0,      &Bs[tid * 8]);
    __syncthreads();
    s16x8 af[2], bfr[4];
#pragma unroll
    for (int i = 0; i < 2; i++) af[i]  = *(const s16x8*)&As[(wid * 32 + i * 16 + lr) * 32 + kg * 8];
#pragma unroll
    for (int j = 0; j < 4; j++) bfr[j] = *(const s16x8*)&Bs[(j * 16 + lr) * 32 + kg * 8];
#pragma unroll
    for (int i = 0; i < 2; i++)
#pragma unroll
      for (int j = 0; j < 4; j++)
        acc[i][j] = __builtin_amdgcn_mfma_f32_16x16x32_bf16(af[i], bfr[j], acc[i][j], 0, 0, 0);
  }
#pragma unroll
  for (int i = 0; i < 2; i++)
#pragma unroll
    for (int j = 0; j < 4; j++)
#pragma unroll
      for (int e = 0; e < 4; e++) {
        int t = brow + wid * 32 + i * 16 + kg * 4 + e;
        int d = j * 16 + lr;
        attn[((size_t)t * BB + b) * EE + h * DD + d] = f2bf(acc[i][j][e]);
      }
}

// ---------------------------------------------------------------- output projection
__global__ __launch_bounds__(256) void gemm_out(
    const ushort* __restrict__ A, const ushort* __restrict__ W,
    const float* __restrict__ bias, float* __restrict__ out)
{
  __shared__ ushort As[128 * 32];
  __shared__ ushort Bs[128 * 32];
  const int K = EE;
  int tid = threadIdx.x;
  int bn = blockIdx.x, bm = blockIdx.y;
  int brow = bm * 128, bcol = bn * 128;
  int lane = tid & 63, wid = tid >> 6;
  int wm = wid >> 1, wn = wid & 1;
  int lr = lane & 15, kg = lane >> 4;

  f32x4 zero = {0.f, 0.f, 0.f, 0.f};
  f32x4 acc[4][4];
#pragma unroll
  for (int i = 0; i < 4; i++)
#pragma unroll
    for (int j = 0; j < 4; j++) acc[i][j] = zero;

  int r0 = tid >> 2, c0 = (tid & 3) * 8;
  const ushort* Abase = A + (size_t)brow * K;
  const ushort* Wbase = W + (size_t)bcol * K;

  for (int k0 = 0; k0 < K; k0 += 32) {
    __syncthreads();
    GL2L(Abase + (size_t)r0 * K + k0 + c0,        &As[tid * 8]);
    GL2L(Abase + (size_t)(r0 + 64) * K + k0 + c0, &As[(tid + 256) * 8]);
    GL2L(Wbase + (size_t)r0 * K + k0 + c0,        &Bs[tid * 8]);
    GL2L(Wbase + (size_t)(r0 + 64) * K + k0 + c0, &Bs[(tid + 256) * 8]);
    __syncthreads();
    s16x8 af[4], bfr[4];
#pragma unroll
    for (int i = 0; i < 4; i++) af[i]  = *(const s16x8*)&As[(wm * 64 + i * 16 + lr) * 32 + kg * 8];
#pragma unroll
    for (int j = 0; j < 4; j++) bfr[j] = *(const s16x8*)&Bs[(wn * 64 + j * 16 + lr) * 32 + kg * 8];
#pragma unroll
    for (int i = 0; i < 4; i++)
#pragma unroll
      for (int j = 0; j < 4; j++)
        acc[i][j] = __builtin_amdgcn_mfma_f32_16x16x32_bf16(af[i], bfr[j], acc[i][j], 0, 0, 0);
  }

#pragma unroll
  for (int i = 0; i < 4; i++)
#pragma unroll
    for (int j = 0; j < 4; j++) {
      int n = bcol + wn * 64 + j * 16 + lr;
      float bv = bias[n];
#pragma unroll
      for (int e = 0; e < 4; e++) {
        int m = brow + wm * 64 + i * 16 + kg * 4 + e;
        out[(size_t)m * EE + n] = acc[i][j][e] + bv;
      }
    }
}

// ---------------------------------------------------------------- launch
extern "C" void kernel_launch(void* const* d_in, const int* in_sizes, int n_in,
                              void* d_out, int out_size, void* d_ws, size_t ws_size,
                              hipStream_t stream) {
  const float* x  = (const float*)d_in[0];
  const float* w1 = (const float*)d_in[1];
  const float* b1 = (const float*)d_in[2];
  const float* w2 = (const float*)d_in[3];
  const float* b2 = (const float*)d_in[4];
  float* out = (float*)d_out;
  float* avg = out + (size_t)MR * EE;

  char* p = (char*)d_ws;
  ushort* Xb   = (ushort*)p; p += (size_t)MR * EE * 2;
  ushort* W1b  = (ushort*)p; p += (size_t)3 * EE * EE * 2;
  ushort* W2b  = (ushort*)p; p += (size_t)EE * EE * 2;
  ushort* Qb   = (ushort*)p; p += (size_t)BB * HH * TT * DD * 2;
  ushort* Kb   = (ushort*)p; p += (size_t)BB * HH * TT * DD * 2;
  ushort* Vt   = (ushort*)p; p += (size_t)BB * HH * TT * DD * 2;
  ushort* attn = (ushort*)p; p += (size_t)MR * EE * 2;
  ushort* Wbuf = (ushort*)p;
  size_t base = (size_t)(p - (char*)d_ws);
  size_t wb1 = (size_t)HH * TT * TT * 2;   // 128 MB per batch
  int nbp = 1;
  if (ws_size >= base + 4 * wb1) nbp = 4;
  else if (ws_size >= base + 2 * wb1) nbp = 2;

  cast_f32_bf16<<<1024, 256, 0, stream>>>(x,  Xb,  MR * EE / 4);
  cast_f32_bf16<<<512,  256, 0, stream>>>(w1, W1b, 3 * EE * EE / 4);
  cast_f32_bf16<<<256,  256, 0, stream>>>(w2, W2b, EE * EE / 4);
  gemm_qkv<<<dim3(24, 64), 256, 0, stream>>>(Xb, W1b, b1, Qb, Kb, Vt);
  for (int b0 = 0; b0 < BB; b0 += nbp) {
    int nb = (BB - b0 < nbp) ? (BB - b0) : nbp;
    attn_scores<<<dim3(128, 16, nb), 256, 0, stream>>>(Qb, Kb, Wbuf, b0);
    avg_kernel<<<2048, 256, 0, stream>>>(Wbuf, avg + (size_t)b0 * TT * TT, nb);
    gemm_pv<<<dim3(16, 16, nb), 256, 0, stream>>>(Wbuf, Vt, attn, b0);
  }
  gemm_out<<<dim3(8, 64), 256, 0, stream>>>(attn, W2b, b2, out);
}

// Round 2
// 702.508 us; speedup vs baseline: 1.1017x; 1.1017x over previous
//
#include <hip/hip_runtime.h>
#include <hip/hip_bf16.h>
#include <cstdint>
#include <cstddef>

typedef __attribute__((ext_vector_type(8))) short s16x8;
typedef __attribute__((ext_vector_type(4))) float f32x4;
typedef __attribute__((ext_vector_type(8))) _Float16 h8;
typedef __attribute__((ext_vector_type(4))) _Float16 h4;

#define TT 2048
#define BB 4
#define EE 1024
#define HH 16
#define DD 64
#define MR 8192   // T*B rows

#define MFMA_BF16(a,b,c) __builtin_amdgcn_mfma_f32_16x16x32_bf16(a,b,c,0,0,0)
#define MFMA_F16(a,b,c)  __builtin_amdgcn_mfma_f32_16x16x32_f16(a,b,c,0,0,0)

__device__ __forceinline__ ushort f2bf(float f) {
  uint32_t u = __float_as_uint(f);
  u += 0x7fffu + ((u >> 16) & 1u);   // RNE
  return (ushort)(u >> 16);
}

// global -> LDS async copy, 16B per lane. LDS dest must be wave-uniform base + lane*16.
#define GL2L(g, l) __builtin_amdgcn_global_load_lds( \
    (__attribute__((address_space(1))) void*)(g), \
    (__attribute__((address_space(3))) void*)(l), 16, 0, 0)

// ---------------------------------------------------------------- cast fp32->bf16
__global__ void cast_f32_bf16(const float* __restrict__ in, ushort* __restrict__ out, int n4) {
  int stride = gridDim.x * blockDim.x;
  for (int i = blockIdx.x * blockDim.x + threadIdx.x; i < n4; i += stride) {
    float4 v = ((const float4*)in)[i];
    ushort4 o;
    o.x = f2bf(v.x); o.y = f2bf(v.y); o.z = f2bf(v.z); o.w = f2bf(v.w);
    ((ushort4*)out)[i] = o;
  }
}

// ---------------------------------------------------------------- QKV projection
// C[m][n] = sum_k A[m][k]*W[n][k] + bias[n];  m=(t*4+b), n = sec*1024 + h*64 + d
// Q scaled by 0.125 -> bf16 [b][h][t][d]; K -> bf16 same; V -> f16 transposed [b][h][d][t].
__global__ __launch_bounds__(256) void gemm_qkv(
    const ushort* __restrict__ A, const ushort* __restrict__ W,
    const float* __restrict__ bias,
    ushort* __restrict__ Qb, ushort* __restrict__ Kb, ushort* __restrict__ Vt)
{
  __shared__ ushort As[128 * 32];
  __shared__ ushort Bs[128 * 32];
  const int K = EE;
  int tid = threadIdx.x;
  int bn = blockIdx.x, bm = blockIdx.y;
  int brow = bm * 128, bcol = bn * 128;
  int lane = tid & 63, wid = tid >> 6;
  int wm = wid >> 1, wn = wid & 1;
  int lr = lane & 15, kg = lane >> 4;

  f32x4 zero = {0.f, 0.f, 0.f, 0.f};
  f32x4 acc[4][4];
#pragma unroll
  for (int i = 0; i < 4; i++)
#pragma unroll
    for (int j = 0; j < 4; j++) acc[i][j] = zero;

  int r0 = tid >> 2, c0 = (tid & 3) * 8;
  const ushort* Abase = A + (size_t)brow * K;
  const ushort* Wbase = W + (size_t)bcol * K;

  for (int k0 = 0; k0 < K; k0 += 32) {
    __syncthreads();
    GL2L(Abase + (size_t)r0 * K + k0 + c0,        &As[tid * 8]);
    GL2L(Abase + (size_t)(r0 + 64) * K + k0 + c0, &As[(tid + 256) * 8]);
    GL2L(Wbase + (size_t)r0 * K + k0 + c0,        &Bs[tid * 8]);
    GL2L(Wbase + (size_t)(r0 + 64) * K + k0 + c0, &Bs[(tid + 256) * 8]);
    __syncthreads();
    s16x8 af[4], bfr[4];
#pragma unroll
    for (int i = 0; i < 4; i++) af[i]  = *(const s16x8*)&As[(wm * 64 + i * 16 + lr) * 32 + kg * 8];
#pragma unroll
    for (int j = 0; j < 4; j++) bfr[j] = *(const s16x8*)&Bs[(wn * 64 + j * 16 + lr) * 32 + kg * 8];
#pragma unroll
    for (int i = 0; i < 4; i++)
#pragma unroll
      for (int j = 0; j < 4; j++)
        acc[i][j] = MFMA_BF16(af[i], bfr[j], acc[i][j]);
  }

#pragma unroll
  for (int i = 0; i < 4; i++)
#pragma unroll
    for (int j = 0; j < 4; j++) {
      int n = bcol + wn * 64 + j * 16 + lr;
      float bv = bias[n];
      int sec = n >> 10;
      int hd = n & 1023;
      int h = hd >> 6, d = hd & 63;
#pragma unroll
      for (int e = 0; e < 4; e++) {
        int m = brow + wm * 64 + i * 16 + kg * 4 + e;
        int t = m >> 2, b = m & 3;
        float v = acc[i][j][e] + bv;
        size_t hoff = (size_t)(b * HH + h);
        if (sec == 0)      Qb[(hoff * TT + t) * DD + d] = f2bf(v * 0.125f);
        else if (sec == 1) Kb[(hoff * TT + t) * DD + d] = f2bf(v);
        else { _Float16 hv = (_Float16)v; Vt[(hoff * DD + d) * TT + t] = *(ushort*)&hv; }
      }
    }
}

// ---------------------------------------------------------------- fused attention
// block = (qt, b): 32 q-rows x all 2048 keys x all 16 heads.
// Per head: QK^T (swapped mfma -> packed b64 LDS writes, XOR swizzle), softmax
// (unnormalized exp kept in LDS f16), avg f32 RMW direct into output, PV f16 MFMA
// with (d-tile, k-half) waves + LDS partial reduction.
__global__ __launch_bounds__(512) void attn_fused(
    const ushort* __restrict__ Qb, const ushort* __restrict__ Kb,
    const _Float16* __restrict__ Vt, ushort* __restrict__ attn,
    float* __restrict__ avgp)
{
  __shared__ _Float16 sc[32 * 2048];   // 128 KB, column-swizzled: col ^ ((row&7)<<3)
  __shared__ float scr[2048];          // 8 KB PV partial-reduction scratch
  __shared__ float invl[32];

  const int qt = blockIdx.x;      // 0..63
  const int b  = blockIdx.y;      // 0..3
  const int tid = threadIdx.x;
  const int lane = tid & 63;
  const int w = tid >> 6;         // wave 0..7
  const int m = lane & 15;
  const int kq = lane >> 4;       // frag k-chunk == C-layout row group
  const int t0 = qt * 32;

  for (int h = 0; h < HH; ++h) {
    const size_t bh = (size_t)b * HH + h;

    // ---- Q fragments (bf16), Q pre-scaled by 1/8
    const ushort* qp = Qb + (bh * TT + t0) * DD;
    s16x8 q00 = *(const s16x8*)&qp[(size_t)m * DD + kq * 8];
    s16x8 q01 = *(const s16x8*)&qp[(size_t)m * DD + 32 + kq * 8];
    s16x8 q10 = *(const s16x8*)&qp[(size_t)(16 + m) * DD + kq * 8];
    s16x8 q11 = *(const s16x8*)&qp[(size_t)(16 + m) * DD + 32 + kq * 8];

    // ---- QK^T: wave w owns k-tiles w*16 .. w*16+15 (keys w*256..+255)
    const ushort* kbase = Kb + bh * TT * DD;
#pragma unroll 4
    for (int i = 0; i < 16; ++i) {
      int nt = w * 16 + i;
      const ushort* kr = kbase + (size_t)(nt * 16 + m) * DD + kq * 8;
      s16x8 a0 = *(const s16x8*)kr;
      s16x8 a1 = *(const s16x8*)(kr + 32);
      f32x4 c0 = {0.f, 0.f, 0.f, 0.f}, c1 = {0.f, 0.f, 0.f, 0.f};
      c0 = MFMA_BF16(a0, q00, c0); c0 = MFMA_BF16(a1, q01, c0);
      c1 = MFMA_BF16(a0, q10, c1); c1 = MFMA_BF16(a1, q11, c1);
      // lane holds S[k = nt*16 + kq*4 + e][q = m (+16)] -> 4 k-consecutive f16, packed write
      int ksw = (nt * 16 + kq * 4) ^ ((m & 7) << 3);
      h4 p0, p1;
#pragma unroll
      for (int e = 0; e < 4; e++) { p0[e] = (_Float16)c0[e]; p1[e] = (_Float16)c1[e]; }
      *(h4*)&sc[(size_t)m * 2048 + ksw] = p0;
      *(h4*)&sc[(size_t)(16 + m) * 2048 + ksw] = p1;
    }
    __syncthreads();

    // ---- softmax: wave w owns rows w*4 .. w*4+3; store UNNORMALIZED exp back
#pragma unroll
    for (int u = 0; u < 4; ++u) {
      int r = w * 4 + u;
      _Float16* rp = &sc[(size_t)r * 2048];
      int xr = (r & 7) << 3;
      float mx = -3e38f;
      h8 v[4];
#pragma unroll
      for (int c = 0; c < 4; ++c) {
        v[c] = *(const h8*)&rp[((c * 64 + lane) * 8) ^ xr];
#pragma unroll
        for (int j = 0; j < 8; j++) mx = fmaxf(mx, (float)v[c][j]);
      }
#pragma unroll
      for (int o = 32; o; o >>= 1) mx = fmaxf(mx, __shfl_xor(mx, o));
      float l = 0.f;
#pragma unroll
      for (int c = 0; c < 4; ++c) {
        h8 ev;
#pragma unroll
        for (int j = 0; j < 8; j++) { float e = __expf((float)v[c][j] - mx); l += e; ev[j] = (_Float16)e; }
        *(h8*)&rp[((c * 64 + lane) * 8) ^ xr] = ev;
      }
#pragma unroll
      for (int o = 32; o; o >>= 1) l += __shfl_xor(l, o);
      if (lane == 0) invl[r] = 1.0f / l;
    }
    __syncthreads();

    // ---- avg: f32 RMW directly into output slice (block-exclusive rows)
    {
      int row = tid >> 4;
      int cb = tid & 15;
      float s = invl[row] * 0.0625f;
      int xr = (row & 7) << 3;
      float4* gp = (float4*)(avgp + ((size_t)b * TT + t0 + row) * TT);
      const _Float16* rp = &sc[(size_t)row * 2048];
#pragma unroll 8
      for (int j = 0; j < 32; ++j) {
        int c4 = cb + j * 16;
        h4 vv = *(const h4*)&rp[(c4 * 4) ^ xr];
        float4 a = {vv[0] * s, vv[1] * s, vv[2] * s, vv[3] * s};
        if (h) { float4 o = gp[c4]; a.x += o.x; a.y += o.y; a.z += o.z; a.w += o.w; }
        gp[c4] = a;
      }
    }

    // ---- PV: wave = (d-tile, k-half); both q-tiles per wave; V (f16) read once
    {
      int dtl = w & 3, kh = w >> 2;
      const _Float16* vb = Vt + bh * DD * TT + (size_t)(dtl * 16 + m) * TT + kh * 1024 + kq * 8;
      const _Float16* a0p = &sc[(size_t)m * 2048];
      const _Float16* a1p = &sc[(size_t)(16 + m) * 2048];
      int xr = (m & 7) << 3;
      f32x4 acc0 = {0.f, 0.f, 0.f, 0.f}, acc1 = {0.f, 0.f, 0.f, 0.f};
#pragma unroll 4
      for (int s = 0; s < 32; ++s) {
        int ksw = (kh * 1024 + s * 32 + kq * 8) ^ xr;
        h8 bv = *(const h8*)(vb + s * 32);
        h8 a0 = *(const h8*)&a0p[ksw];
        h8 a1 = *(const h8*)&a1p[ksw];
        acc0 = MFMA_F16(a0, bv, acc0);
        acc1 = MFMA_F16(a1, bv, acc1);
      }
      if (kh == 1) {
#pragma unroll
        for (int e = 0; e < 4; e++) {
          scr[(dtl * 2 + 0) * 256 + (kq * 4 + e) * 16 + m] = acc0[e];
          scr[(dtl * 2 + 1) * 256 + (kq * 4 + e) * 16 + m] = acc1[e];
        }
      }
      __syncthreads();
      if (kh == 0) {
#pragma unroll
        for (int e = 0; e < 4; e++) {
          int ql = kq * 4 + e;
          float v0 = (acc0[e] + scr[(dtl * 2 + 0) * 256 + ql * 16 + m]) * invl[ql];
          float v1 = (acc1[e] + scr[(dtl * 2 + 1) * 256 + ql * 16 + m]) * invl[16 + ql];
          attn[((size_t)(t0 + ql) * BB + b) * EE + h * DD + dtl * 16 + m] = f2bf(v0);
          attn[((size_t)(t0 + 16 + ql) * BB + b) * EE + h * DD + dtl * 16 + m] = f2bf(v1);
        }
      }
    }
    __syncthreads();   // sc/scr reads done before next head overwrites
  }
}

// ---------------------------------------------------------------- output projection
__global__ __launch_bounds__(256) void gemm_out(
    const ushort* __restrict__ A, const ushort* __restrict__ W,
    const float* __restrict__ bias, float* __restrict__ out)
{
  __shared__ ushort As[128 * 32];
  __shared__ ushort Bs[128 * 32];
  const int K = EE;
  int tid = threadIdx.x;
  int bn = blockIdx.x, bm = blockIdx.y;
  int brow = bm * 128, bcol = bn * 128;
  int lane = tid & 63, wid = tid >> 6;
  int wm = wid >> 1, wn = wid & 1;
  int lr = lane & 15, kg = lane >> 4;

  f32x4 zero = {0.f, 0.f, 0.f, 0.f};
  f32x4 acc[4][4];
#pragma unroll
  for (int i = 0; i < 4; i++)
#pragma unroll
    for (int j = 0; j < 4; j++) acc[i][j] = zero;

  int r0 = tid >> 2, c0 = (tid & 3) * 8;
  const ushort* Abase = A + (size_t)brow * K;
  const ushort* Wbase = W + (size_t)bcol * K;

  for (int k0 = 0; k0 < K; k0 += 32) {
    __syncthreads();
    GL2L(Abase + (size_t)r0 * K + k0 + c0,        &As[tid * 8]);
    GL2L(Abase + (size_t)(r0 + 64) * K + k0 + c0, &As[(tid + 256) * 8]);
    GL2L(Wbase + (size_t)r0 * K + k0 + c0,        &Bs[tid * 8]);
    GL2L(Wbase + (size_t)(r0 + 64) * K + k0 + c0, &Bs[(tid + 256) * 8]);
    __syncthreads();
    s16x8 af[4], bfr[4];
#pragma unroll
    for (int i = 0; i < 4; i++) af[i]  = *(const s16x8*)&As[(wm * 64 + i * 16 + lr) * 32 + kg * 8];
#pragma unroll
    for (int j = 0; j < 4; j++) bfr[j] = *(const s16x8*)&Bs[(wn * 64 + j * 16 + lr) * 32 + kg * 8];
#pragma unroll
    for (int i = 0; i < 4; i++)
#pragma unroll
      for (int j = 0; j < 4; j++)
        acc[i][j] = MFMA_BF16(af[i], bfr[j], acc[i][j]);
  }

#pragma unroll
  for (int i = 0; i < 4; i++)
#pragma unroll
    for (int j = 0; j < 4; j++) {
      int n = bcol + wn * 64 + j * 16 + lr;
      float bv = bias[n];
#pragma unroll
      for (int e = 0; e < 4; e++) {
        int m = brow + wm * 64 + i * 16 + kg * 4 + e;
        out[(size_t)m * EE + n] = acc[i][j][e] + bv;
      }
    }
}

// ---------------------------------------------------------------- launch
extern "C" void kernel_launch(void* const* d_in, const int* in_sizes, int n_in,
                              void* d_out, int out_size, void* d_ws, size_t ws_size,
                              hipStream_t stream) {
  const float* x  = (const float*)d_in[0];
  const float* w1 = (const float*)d_in[1];
  const float* b1 = (const float*)d_in[2];
  const float* w2 = (const float*)d_in[3];
  const float* b2 = (const float*)d_in[4];
  float* out = (float*)d_out;
  float* avg = out + (size_t)MR * EE;

  char* p = (char*)d_ws;
  ushort* Xb   = (ushort*)p; p += (size_t)MR * EE * 2;
  ushort* W1b  = (ushort*)p; p += (size_t)3 * EE * EE * 2;
  ushort* W2b  = (ushort*)p; p += (size_t)EE * EE * 2;
  ushort* Qb   = (ushort*)p; p += (size_t)BB * HH * TT * DD * 2;
  ushort* Kb   = (ushort*)p; p += (size_t)BB * HH * TT * DD * 2;
  ushort* Vt   = (ushort*)p; p += (size_t)BB * HH * TT * DD * 2;
  ushort* attn = (ushort*)p; p += (size_t)MR * EE * 2;
  (void)ws_size;

  cast_f32_bf16<<<1024, 256, 0, stream>>>(x,  Xb,  MR * EE / 4);
  cast_f32_bf16<<<512,  256, 0, stream>>>(w1, W1b, 3 * EE * EE / 4);
  cast_f32_bf16<<<256,  256, 0, stream>>>(w2, W2b, EE * EE / 4);
  gemm_qkv<<<dim3(24, 64), 256, 0, stream>>>(Xb, W1b, b1, Qb, Kb, Vt);
  attn_fused<<<dim3(TT / 32, BB), 512, 0, stream>>>(Qb, Kb, (const _Float16*)Vt, attn, avg);
  gemm_out<<<dim3(8, 64), 256, 0, stream>>>(attn, W2b, b2, out);
}

// Round 3
// 560.601 us; speedup vs baseline: 1.3806x; 1.2531x over previous
//
#include <hip/hip_runtime.h>
#include <hip/hip_bf16.h>
#include <cstdint>
#include <cstddef>

typedef __attribute__((ext_vector_type(8))) short s16x8;
typedef __attribute__((ext_vector_type(4))) float f32x4;
typedef __attribute__((ext_vector_type(8))) float f32x8;
typedef __attribute__((ext_vector_type(8))) _Float16 h8;
typedef __attribute__((ext_vector_type(4))) _Float16 h4;

#define TT 2048
#define BB 4
#define EE 1024
#define HH 16
#define DD 64
#define MR 8192   // T*B rows

#define MFMA_BF16(a,b,c) __builtin_amdgcn_mfma_f32_16x16x32_bf16(a,b,c,0,0,0)
#define MFMA_F16(a,b,c)  __builtin_amdgcn_mfma_f32_16x16x32_f16(a,b,c,0,0,0)

__device__ __forceinline__ ushort f2bf(float f) {
  uint32_t u = __float_as_uint(f);
  u += 0x7fffu + ((u >> 16) & 1u);   // RNE
  return (ushort)(u >> 16);
}

// global -> LDS async copy, 16B per lane. LDS dest must be wave-uniform base + lane*16.
#define GL2L(g, l) __builtin_amdgcn_global_load_lds( \
    (__attribute__((address_space(1))) void*)(g), \
    (__attribute__((address_space(3))) void*)(l), 16, 0, 0)

// ---------------------------------------------------------------- cast fp32->bf16
__global__ void cast_f32_bf16(const float* __restrict__ in, ushort* __restrict__ out, int n4) {
  int stride = gridDim.x * blockDim.x;
  for (int i = blockIdx.x * blockDim.x + threadIdx.x; i < n4; i += stride) {
    float4 v = ((const float4*)in)[i];
    ushort4 o;
    o.x = f2bf(v.x); o.y = f2bf(v.y); o.z = f2bf(v.z); o.w = f2bf(v.w);
    ((ushort4*)out)[i] = o;
  }
}

// ---------------------------------------------------------------- QKV projection
// C[m][n] = sum_k A[m][k]*W[n][k] + bias[n];  m=(t*4+b), n = sec*1024 + h*64 + d
// Q scaled by 0.125 -> bf16 [b][h][t][d]; K -> bf16 same; V -> f16 transposed [b][h][d][t].
__global__ __launch_bounds__(256) void gemm_qkv(
    const ushort* __restrict__ A, const ushort* __restrict__ W,
    const float* __restrict__ bias,
    ushort* __restrict__ Qb, ushort* __restrict__ Kb, ushort* __restrict__ Vt)
{
  __shared__ ushort As[128 * 32];
  __shared__ ushort Bs[128 * 32];
  const int K = EE;
  int tid = threadIdx.x;
  int bn = blockIdx.x, bm = blockIdx.y;
  int brow = bm * 128, bcol = bn * 128;
  int lane = tid & 63, wid = tid >> 6;
  int wm = wid >> 1, wn = wid & 1;
  int lr = lane & 15, kg = lane >> 4;

  f32x4 zero = {0.f, 0.f, 0.f, 0.f};
  f32x4 acc[4][4];
#pragma unroll
  for (int i = 0; i < 4; i++)
#pragma unroll
    for (int j = 0; j < 4; j++) acc[i][j] = zero;

  int r0 = tid >> 2, c0 = (tid & 3) * 8;
  const ushort* Abase = A + (size_t)brow * K;
  const ushort* Wbase = W + (size_t)bcol * K;

  for (int k0 = 0; k0 < K; k0 += 32) {
    __syncthreads();
    GL2L(Abase + (size_t)r0 * K + k0 + c0,        &As[tid * 8]);
    GL2L(Abase + (size_t)(r0 + 64) * K + k0 + c0, &As[(tid + 256) * 8]);
    GL2L(Wbase + (size_t)r0 * K + k0 + c0,        &Bs[tid * 8]);
    GL2L(Wbase + (size_t)(r0 + 64) * K + k0 + c0, &Bs[(tid + 256) * 8]);
    __syncthreads();
    s16x8 af[4], bfr[4];
#pragma unroll
    for (int i = 0; i < 4; i++) af[i]  = *(const s16x8*)&As[(wm * 64 + i * 16 + lr) * 32 + kg * 8];
#pragma unroll
    for (int j = 0; j < 4; j++) bfr[j] = *(const s16x8*)&Bs[(wn * 64 + j * 16 + lr) * 32 + kg * 8];
#pragma unroll
    for (int i = 0; i < 4; i++)
#pragma unroll
      for (int j = 0; j < 4; j++)
        acc[i][j] = MFMA_BF16(af[i], bfr[j], acc[i][j]);
  }

#pragma unroll
  for (int i = 0; i < 4; i++)
#pragma unroll
    for (int j = 0; j < 4; j++) {
      int n = bcol + wn * 64 + j * 16 + lr;
      float bv = bias[n];
      int sec = n >> 10;
      int hd = n & 1023;
      int h = hd >> 6, d = hd & 63;
#pragma unroll
      for (int e = 0; e < 4; e++) {
        int m = brow + wm * 64 + i * 16 + kg * 4 + e;
        int t = m >> 2, b = m & 3;
        float v = acc[i][j][e] + bv;
        size_t hoff = (size_t)(b * HH + h);
        if (sec == 0)      Qb[(hoff * TT + t) * DD + d] = f2bf(v * 0.125f);
        else if (sec == 1) Kb[(hoff * TT + t) * DD + d] = f2bf(v);
        else { _Float16 hv = (_Float16)v; Vt[(hoff * DD + d) * TT + t] = *(ushort*)&hv; }
      }
    }
}

// ---------------------------------------------------------------- fused attention
// block = (qt, b): 32 q-rows x all 2048 keys x all 16 heads.
// Per head: QK^T (swapped mfma -> packed b64 LDS writes, XOR swizzle), softmax
// (unnormalized exp kept in LDS f16) with avg accumulated into REGISTERS
// (written once after the head loop), PV f16 MFMA with (d-tile, k-half) waves.
__global__ __launch_bounds__(512, 2) void attn_fused(
    const ushort* __restrict__ Qb, const ushort* __restrict__ Kb,
    const _Float16* __restrict__ Vt, ushort* __restrict__ attn,
    float* __restrict__ avgp)
{
  __shared__ _Float16 sc[32 * 2048];   // 128 KB, column-swizzled: col ^ ((row&7)<<3)
  __shared__ float scr[2048];          // 8 KB PV partial-reduction scratch
  __shared__ float invl[32];

  const int qt = blockIdx.x;      // 0..63
  const int b  = blockIdx.y;      // 0..3
  const int tid = threadIdx.x;
  const int lane = tid & 63;
  const int w = tid >> 6;         // wave 0..7
  const int m = lane & 15;
  const int kq = lane >> 4;       // frag k-chunk == C-layout row group
  const int t0 = qt * 32;

  // per-thread avg accumulator: rows w*4+u (u=0..3), cols (c*64+lane)*8+j
  f32x8 av[4][4];
#pragma unroll
  for (int u = 0; u < 4; u++)
#pragma unroll
    for (int c = 0; c < 4; c++) av[u][c] = (f32x8)(0.f);

  for (int h = 0; h < HH; ++h) {
    const size_t bh = (size_t)b * HH + h;

    // ---- Q fragments (bf16), Q pre-scaled by 1/8
    const ushort* qp = Qb + (bh * TT + t0) * DD;
    s16x8 q00 = *(const s16x8*)&qp[(size_t)m * DD + kq * 8];
    s16x8 q01 = *(const s16x8*)&qp[(size_t)m * DD + 32 + kq * 8];
    s16x8 q10 = *(const s16x8*)&qp[(size_t)(16 + m) * DD + kq * 8];
    s16x8 q11 = *(const s16x8*)&qp[(size_t)(16 + m) * DD + 32 + kq * 8];

    // ---- QK^T: wave w owns k-tiles w*16 .. w*16+15 (keys w*256..+255)
    const ushort* kbase = Kb + bh * TT * DD;
#pragma unroll 4
    for (int i = 0; i < 16; ++i) {
      int nt = w * 16 + i;
      const ushort* kr = kbase + (size_t)(nt * 16 + m) * DD + kq * 8;
      s16x8 a0 = *(const s16x8*)kr;
      s16x8 a1 = *(const s16x8*)(kr + 32);
      f32x4 c0 = {0.f, 0.f, 0.f, 0.f}, c1 = {0.f, 0.f, 0.f, 0.f};
      c0 = MFMA_BF16(a0, q00, c0); c0 = MFMA_BF16(a1, q01, c0);
      c1 = MFMA_BF16(a0, q10, c1); c1 = MFMA_BF16(a1, q11, c1);
      // lane holds S[k = nt*16 + kq*4 + e][q = m (+16)] -> 4 k-consecutive f16, packed write
      int ksw = (nt * 16 + kq * 4) ^ ((m & 7) << 3);
      h4 p0, p1;
#pragma unroll
      for (int e = 0; e < 4; e++) { p0[e] = (_Float16)c0[e]; p1[e] = (_Float16)c1[e]; }
      *(h4*)&sc[(size_t)m * 2048 + ksw] = p0;
      *(h4*)&sc[(size_t)(16 + m) * 2048 + ksw] = p1;
    }
    __syncthreads();

    // ---- softmax: wave w owns rows w*4 .. w*4+3; store UNNORMALIZED exp back;
    //      fold normalized-weight sum into av[] registers.
#pragma unroll
    for (int u = 0; u < 4; ++u) {
      int r = w * 4 + u;
      _Float16* rp = &sc[(size_t)r * 2048];
      int xr = (r & 7) << 3;
      float mx = -3e38f;
      h8 v[4];
#pragma unroll
      for (int c = 0; c < 4; ++c) {
        v[c] = *(const h8*)&rp[((c * 64 + lane) * 8) ^ xr];
#pragma unroll
        for (int j = 0; j < 8; j++) mx = fmaxf(mx, (float)v[c][j]);
      }
#pragma unroll
      for (int o = 32; o; o >>= 1) mx = fmaxf(mx, __shfl_xor(mx, o));
      float l = 0.f;
      h8 ev[4];
#pragma unroll
      for (int c = 0; c < 4; ++c) {
#pragma unroll
        for (int j = 0; j < 8; j++) { float e = __expf((float)v[c][j] - mx); l += e; ev[c][j] = (_Float16)e; }
        *(h8*)&rp[((c * 64 + lane) * 8) ^ xr] = ev[c];
      }
#pragma unroll
      for (int o = 32; o; o >>= 1) l += __shfl_xor(l, o);
      float inv = 1.0f / l;
      if (lane == 0) invl[r] = inv;
#pragma unroll
      for (int c = 0; c < 4; ++c)
#pragma unroll
        for (int j = 0; j < 8; j++)
          av[u][c][j] += (float)ev[c][j] * inv;
    }
    __syncthreads();

    // ---- PV: wave = (d-tile, k-half); both q-tiles per wave; V (f16) read once
    {
      int dtl = w & 3, kh = w >> 2;
      const _Float16* vb = Vt + bh * DD * TT + (size_t)(dtl * 16 + m) * TT + kh * 1024 + kq * 8;
      const _Float16* a0p = &sc[(size_t)m * 2048];
      const _Float16* a1p = &sc[(size_t)(16 + m) * 2048];
      int xr = (m & 7) << 3;
      f32x4 acc0 = {0.f, 0.f, 0.f, 0.f}, acc1 = {0.f, 0.f, 0.f, 0.f};
#pragma unroll 4
      for (int s = 0; s < 32; ++s) {
        int ksw = (kh * 1024 + s * 32 + kq * 8) ^ xr;
        h8 bv = *(const h8*)(vb + s * 32);
        h8 a0 = *(const h8*)&a0p[ksw];
        h8 a1 = *(const h8*)&a1p[ksw];
        acc0 = MFMA_F16(a0, bv, acc0);
        acc1 = MFMA_F16(a1, bv, acc1);
      }
      if (kh == 1) {
#pragma unroll
        for (int e = 0; e < 4; e++) {
          scr[(dtl * 2 + 0) * 256 + (kq * 4 + e) * 16 + m] = acc0[e];
          scr[(dtl * 2 + 1) * 256 + (kq * 4 + e) * 16 + m] = acc1[e];
        }
      }
      __syncthreads();
      if (kh == 0) {
#pragma unroll
        for (int e = 0; e < 4; e++) {
          int ql = kq * 4 + e;
          float v0 = (acc0[e] + scr[(dtl * 2 + 0) * 256 + ql * 16 + m]) * invl[ql];
          float v1 = (acc1[e] + scr[(dtl * 2 + 1) * 256 + ql * 16 + m]) * invl[16 + ql];
          attn[((size_t)(t0 + ql) * BB + b) * EE + h * DD + dtl * 16 + m] = f2bf(v0);
          attn[((size_t)(t0 + 16 + ql) * BB + b) * EE + h * DD + dtl * 16 + m] = f2bf(v1);
        }
      }
    }
    __syncthreads();   // sc/scr reads done before next head overwrites
  }

  // ---- write avg once: row t0 + w*4+u, cols (c*64+lane)*8 .. +7
#pragma unroll
  for (int u = 0; u < 4; ++u) {
    float* gp = avgp + ((size_t)b * TT + t0 + w * 4 + u) * TT;
#pragma unroll
    for (int c = 0; c < 4; ++c) {
      int cb = (c * 64 + lane) * 8;
      float4 o0 = {av[u][c][0] * 0.0625f, av[u][c][1] * 0.0625f,
                   av[u][c][2] * 0.0625f, av[u][c][3] * 0.0625f};
      float4 o1 = {av[u][c][4] * 0.0625f, av[u][c][5] * 0.0625f,
                   av[u][c][6] * 0.0625f, av[u][c][7] * 0.0625f};
      ((float4*)(gp + cb))[0] = o0;
      ((float4*)(gp + cb))[1] = o1;
    }
  }
}

// ---------------------------------------------------------------- output projection
__global__ __launch_bounds__(256) void gemm_out(
    const ushort* __restrict__ A, const ushort* __restrict__ W,
    const float* __restrict__ bias, float* __restrict__ out)
{
  __shared__ ushort As[128 * 32];
  __shared__ ushort Bs[128 * 32];
  const int K = EE;
  int tid = threadIdx.x;
  int bn = blockIdx.x, bm = blockIdx.y;
  int brow = bm * 128, bcol = bn * 128;
  int lane = tid & 63, wid = tid >> 6;
  int wm = wid >> 1, wn = wid & 1;
  int lr = lane & 15, kg = lane >> 4;

  f32x4 zero = {0.f, 0.f, 0.f, 0.f};
  f32x4 acc[4][4];
#pragma unroll
  for (int i = 0; i < 4; i++)
#pragma unroll
    for (int j = 0; j < 4; j++) acc[i][j] = zero;

  int r0 = tid >> 2, c0 = (tid & 3) * 8;
  const ushort* Abase = A + (size_t)brow * K;
  const ushort* Wbase = W + (size_t)bcol * K;

  for (int k0 = 0; k0 < K; k0 += 32) {
    __syncthreads();
    GL2L(Abase + (size_t)r0 * K + k0 + c0,        &As[tid * 8]);
    GL2L(Abase + (size_t)(r0 + 64) * K + k0 + c0, &As[(tid + 256) * 8]);
    GL2L(Wbase + (size_t)r0 * K + k0 + c0,        &Bs[tid * 8]);
    GL2L(Wbase + (size_t)(r0 + 64) * K + k0 + c0, &Bs[(tid + 256) * 8]);
    __syncthreads();
    s16x8 af[4], bfr[4];
#pragma unroll
    for (int i = 0; i < 4; i++) af[i]  = *(const s16x8*)&As[(wm * 64 + i * 16 + lr) * 32 + kg * 8];
#pragma unroll
    for (int j = 0; j < 4; j++) bfr[j] = *(const s16x8*)&Bs[(wn * 64 + j * 16 + lr) * 32 + kg * 8];
#pragma unroll
    for (int i = 0; i < 4; i++)
#pragma unroll
      for (int j = 0; j < 4; j++)
        acc[i][j] = MFMA_BF16(af[i], bfr[j], acc[i][j]);
  }

#pragma unroll
  for (int i = 0; i < 4; i++)
#pragma unroll
    for (int j = 0; j < 4; j++) {
      int n = bcol + wn * 64 + j * 16 + lr;
      float bv = bias[n];
#pragma unroll
      for (int e = 0; e < 4; e++) {
        int m = brow + wm * 64 + i * 16 + kg * 4 + e;
        out[(size_t)m * EE + n] = acc[i][j][e] + bv;
      }
    }
}

// ---------------------------------------------------------------- launch
extern "C" void kernel_launch(void* const* d_in, const int* in_sizes, int n_in,
                              void* d_out, int out_size, void* d_ws, size_t ws_size,
                              hipStream_t stream) {
  const float* x  = (const float*)d_in[0];
  const float* w1 = (const float*)d_in[1];
  const float* b1 = (const float*)d_in[2];
  const float* w2 = (const float*)d_in[3];
  const float* b2 = (const float*)d_in[4];
  float* out = (float*)d_out;
  float* avg = out + (size_t)MR * EE;

  char* p = (char*)d_ws;
  ushort* Xb   = (ushort*)p; p += (size_t)MR * EE * 2;
  ushort* W1b  = (ushort*)p; p += (size_t)3 * EE * EE * 2;
  ushort* W2b  = (ushort*)p; p += (size_t)EE * EE * 2;
  ushort* Qb   = (ushort*)p; p += (size_t)BB * HH * TT * DD * 2;
  ushort* Kb   = (ushort*)p; p += (size_t)BB * HH * TT * DD * 2;
  ushort* Vt   = (ushort*)p; p += (size_t)BB * HH * TT * DD * 2;
  ushort* attn = (ushort*)p; p += (size_t)MR * EE * 2;
  (void)ws_size;

  cast_f32_bf16<<<1024, 256, 0, stream>>>(x,  Xb,  MR * EE / 4);
  cast_f32_bf16<<<512,  256, 0, stream>>>(w1, W1b, 3 * EE * EE / 4);
  cast_f32_bf16<<<256,  256, 0, stream>>>(w2, W2b, EE * EE / 4);
  gemm_qkv<<<dim3(24, 64), 256, 0, stream>>>(Xb, W1b, b1, Qb, Kb, Vt);
  attn_fused<<<dim3(TT / 32, BB), 512, 0, stream>>>(Qb, Kb, (const _Float16*)Vt, attn, avg);
  gemm_out<<<dim3(8, 64), 256, 0, stream>>>(attn, W2b, b2, out);
}